// Round 5
// baseline (241.432 us; speedup 1.0000x reference)
//
#include <hip/hip_runtime.h>
#include <math.h>

#define L_IN     262144
#define N_FRAME  1024
#define AMIN     1e-10f
#define DRANGE   80.0f
#define UNITS_CH 1056            // (32 frames * 256 hop + 256)/8 16B-units per channel
#define WS_HI_OFF   4096
#define WS_HALF     524288       // 16 frags * 32 kk * 64 lanes * 16B

typedef short bf16x8 __attribute__((ext_vector_type(8)));
typedef float f32x16 __attribute__((ext_vector_type(16)));

__device__ __forceinline__ short f2bf(float f) {           // fp32 -> bf16 RNE
    unsigned u = __float_as_uint(f);
    u = (u + 0x7FFFu + ((u >> 16) & 1u)) >> 16;
    return (short)u;
}
__device__ __forceinline__ float bf2f(short h) {
    return __uint_as_float(((unsigned)(unsigned short)h) << 16);
}
__device__ __forceinline__ int swz(int u) { return u ^ ((u >> 5) & 7); }

// W -> bf16 hi/lo in 32x32x16 MFMA B-frag order.
// frag fi = g*2+nf (g = filter group of 32, nf: 0=cos, 1=sin).
// unit ((fi*32+kk)*64+lane)*16B holds B[n=lane&31][k=kk*16+(lane>>5)*8+j].
// Special: fi==1 (g0 sin), n==0 column is filter-0 sin == all zeros -> holds
// the Nyquist (f=256) cos weights instead.
__global__ __launch_bounds__(256) void wconv_kernel(
    const float* __restrict__ kr, const float* __restrict__ ki,
    short* __restrict__ whi, short* __restrict__ wlo, unsigned* __restrict__ wsmax)
{
    if (blockIdx.x == 0 && threadIdx.x == 0) wsmax[0] = 0u;
    const int tid  = threadIdx.x;
    const int pair = blockIdx.x * 4 + (tid >> 6);   // (fi,kk) in [0,512)
    const int lane = tid & 63;
    const int fi = pair >> 5, kk = pair & 31;
    const int g = fi >> 1, nf = fi & 1;
    const int n  = lane & 31;
    const int k0 = kk * 16 + (lane >> 5) * 8;
    const int f  = g * 32 + n;
    bf16x8 h8, l8;
    #pragma unroll
    for (int j = 0; j < 8; ++j) {
        const int k = k0 + j;
        float w;
        if (nf == 1 && g == 0 && n == 0) w = kr[k * 257 + 256];   // Nyquist column
        else                             w = (nf ? ki : kr)[k * 257 + f];
        short hh = f2bf(w);
        h8[j] = hh;
        l8[j] = f2bf(w - bf2f(hh));
    }
    const int off = ((fi * 32 + kk) * 64 + lane) * 8;
    *(bf16x8*)(whi + off) = h8;
    *(bf16x8*)(wlo + off) = l8;
}

// One block: 32 frames x 2 channels (M=64, frag mf = channel) x all 257 filters.
// 8 waves; wave wv owns filter group g=wv. Register-lean: no B dbuf, kh
// serialized -> target <=128 regs/wave incl. 64 acc AGPRs => 16 waves/CU.
__global__ __launch_bounds__(512, 4) void spec_kernel(
    const float* __restrict__ x,
    const short* __restrict__ whi, const short* __restrict__ wlo,
    float* __restrict__ out, unsigned* __restrict__ wsmax)
{
    __shared__ short Ah[2 * UNITS_CH * 8];   // 33.8 KB
    __shared__ short Al[2 * UNITS_CH * 8];   // 33.8 KB
    __shared__ float wmax[8];

    const int blk = blockIdx.x;
    const int tt  = blk & 31;
    const int b   = blk >> 5;
    const int tid = threadIdx.x;
    const int lane = tid & 63;
    const int col  = lane & 31;
    const int half = lane >> 5;

    // ---- stage A: 8448 samples/channel -> bf16 hi/lo, swizzled 16B units ----
    const int s_origin = tt * 8192 - 128;
    const bool interior = (tt > 0) && (tt < 31);
    for (int U = tid; U < 2 * UNITS_CH; U += 512) {
        const int ch = (U >= UNITS_CH) ? 1 : 0;
        const int u  = U - ch * UNITS_CH;
        const int g0 = s_origin + u * 8;
        const float* xp = x + ((size_t)b * 2 + ch) * L_IN;
        float v[8];
        if (interior) {
            float4 p0 = *(const float4*)(xp + g0);
            float4 p1 = *(const float4*)(xp + g0 + 4);
            v[0]=p0.x; v[1]=p0.y; v[2]=p0.z; v[3]=p0.w;
            v[4]=p1.x; v[5]=p1.y; v[6]=p1.z; v[7]=p1.w;
        } else {
            #pragma unroll
            for (int j = 0; j < 8; ++j) {
                const int idx = g0 + j;
                v[j] = (idx >= 0 && idx < L_IN) ? xp[idx] : 0.0f;
            }
        }
        bf16x8 h8, l8;
        #pragma unroll
        for (int j = 0; j < 8; ++j) {
            short hh = f2bf(v[j]);
            h8[j] = hh;
            l8[j] = f2bf(v[j] - bf2f(hh));
        }
        const int su = swz(u);
        *(bf16x8*)&Ah[(ch * UNITS_CH + su) * 8] = h8;
        *(bf16x8*)&Al[(ch * UNITS_CH + su) * 8] = l8;
    }
    __syncthreads();

    // ---- K loop: 32 steps, barrier-free, register-lean ----
    const int g = __builtin_amdgcn_readfirstlane(tid >> 6);
    const int bc = (g * 2 + 0) * 32 * 512;        // cos frag base (elements)
    const int bs = (g * 2 + 1) * 32 * 512;        // sin frag base
    const int lo8 = lane * 8;

    f32x16 acc[2][2];
    #pragma unroll
    for (int mf = 0; mf < 2; ++mf)
        #pragma unroll
        for (int nf = 0; nf < 2; ++nf)
            #pragma unroll
            for (int r = 0; r < 16; ++r) acc[mf][nf][r] = 0.0f;

    #pragma unroll 4
    for (int s = 0; s < 32; ++s) {
        bf16x8 ah[2], al[2];
        #pragma unroll
        for (int mf = 0; mf < 2; ++mf) {
            const int e = (mf * UNITS_CH + swz(col * 32 + s * 2 + half)) * 8;
            ah[mf] = *(const bf16x8*)&Ah[e];
            al[mf] = *(const bf16x8*)&Al[e];
        }
        bf16x8 bh[2], bl[2];
        {
            const int oc = bc + s * 512 + lo8;
            const int os = bs + s * 512 + lo8;
            bh[0] = *(const bf16x8*)(whi + oc);
            bl[0] = *(const bf16x8*)(wlo + oc);
            bh[1] = *(const bf16x8*)(whi + os);
            bl[1] = *(const bf16x8*)(wlo + os);
        }
        // pass-major: hh, lh, hl — same-acc dependents 4 apart
        #pragma unroll
        for (int mf = 0; mf < 2; ++mf)
            #pragma unroll
            for (int nf = 0; nf < 2; ++nf)
                acc[mf][nf] = __builtin_amdgcn_mfma_f32_32x32x16_bf16(ah[mf], bh[nf], acc[mf][nf], 0, 0, 0);
        #pragma unroll
        for (int mf = 0; mf < 2; ++mf)
            #pragma unroll
            for (int nf = 0; nf < 2; ++nf)
                acc[mf][nf] = __builtin_amdgcn_mfma_f32_32x32x16_bf16(al[mf], bh[nf], acc[mf][nf], 0, 0, 0);
        #pragma unroll
        for (int mf = 0; mf < 2; ++mf)
            #pragma unroll
            for (int nf = 0; nf < 2; ++nf)
                acc[mf][nf] = __builtin_amdgcn_mfma_f32_32x32x16_bf16(ah[mf], bl[nf], acc[mf][nf], 0, 0, 0);
    }

    // ---- epilogue: p = re^2+im^2, store, track max ----
    // C/D layout (32x32): n = lane&31, m = (r&3) + 8*(r>>2) + 4*(lane>>5)
    const bool nyq = (g == 0) && (col == 0);
    float pmax = 0.0f;
    #pragma unroll
    for (int mf = 0; mf < 2; ++mf) {          // mf = channel
        const int f = g * 32 + col;
        #pragma unroll
        for (int r = 0; r < 16; ++r) {
            const int m = (r & 3) + 8 * (r >> 2) + 4 * half;
            const int t = tt * 32 + m;
            const float re = acc[mf][0][r];
            const float im = acc[mf][1][r];
            const float imq = nyq ? 0.0f : im;
            float p = fmaxf(re * re + imq * imq, AMIN);
            pmax = fmaxf(pmax, p);
            out[(((size_t)b * 257 + f) * N_FRAME + t) * 2 + mf] = p;
            if (nyq) {                         // sin-frag col0 carries f=256 re
                float pn = fmaxf(im * im, AMIN);
                pmax = fmaxf(pmax, pn);
                out[(((size_t)b * 257 + 256) * N_FRAME + t) * 2 + mf] = pn;
            }
        }
    }

    #pragma unroll
    for (int off = 32; off > 0; off >>= 1)
        pmax = fmaxf(pmax, __shfl_down(pmax, off, 64));
    if (lane == 0) wmax[tid >> 6] = pmax;
    __syncthreads();
    if (tid == 0) {
        float m2 = wmax[0];
        #pragma unroll
        for (int w = 1; w < 8; ++w) m2 = fmaxf(m2, wmax[w]);
        atomicMax(wsmax, __float_as_uint(m2));
    }
}

__global__ __launch_bounds__(256) void finalize_kernel(
    float* __restrict__ out, const unsigned* __restrict__ ws_max, int n4)
{
    const int i = blockIdx.x * 256 + threadIdx.x;
    if (i >= n4) return;
    const float mlog = 10.0f * log10f(__uint_as_float(*ws_max));
    float4 p = ((const float4*)out)[i];
    float4 v;
    v.x = fmaxf(10.0f * log10f(p.x) - mlog, -DRANGE);
    v.y = fmaxf(10.0f * log10f(p.y) - mlog, -DRANGE);
    v.z = fmaxf(10.0f * log10f(p.z) - mlog, -DRANGE);
    v.w = fmaxf(10.0f * log10f(p.w) - mlog, -DRANGE);
    ((float4*)out)[i] = v;
}

extern "C" void kernel_launch(void* const* d_in, const int* in_sizes, int n_in,
                              void* d_out, int out_size, void* d_ws, size_t ws_size,
                              hipStream_t stream) {
    const float* x  = (const float*)d_in[0];
    const float* kr = (const float*)d_in[1];
    const float* ki = (const float*)d_in[2];
    float* out      = (float*)d_out;

    unsigned* wsmax = (unsigned*)d_ws;
    short* whi      = (short*)((char*)d_ws + WS_HI_OFF);
    short* wlo      = (short*)((char*)d_ws + WS_HI_OFF + WS_HALF);

    wconv_kernel<<<128, 256, 0, stream>>>(kr, ki, whi, wlo, wsmax);

    const int nblocks = 32 * 32;       // b * t-tiles
    spec_kernel<<<nblocks, 512, 0, stream>>>(x, whi, wlo, out, wsmax);

    const int n4 = out_size / 4;
    finalize_kernel<<<(n4 + 255) / 256, 256, 0, stream>>>(out, wsmax, n4);
}